// Round 6
// baseline (287.907 us; speedup 1.0000x reference)
//
#include <hip/hip_runtime.h>
#include <stdint.h>

// ---------------------------------------------------------------------------
// LazyGGUFLinear: y = x @ dequant(scales, codes)^T   (M=N=K=4096)
// R8: template-exact m201 schedule. R2/R4/R7 (three different read/wait
//     structures, all motion-pinned by sched_barrier(0) or "memory"-clobbered
//     asm) all measured ~5200 cy/K-tile = MFMA floor + LDS-port floor
//     SERIALIZED. The verified m201 phase has NO sched fences and NO memory
//     clobbers -- scheduler freedom around the clobber-free s_barrier is what
//     lets the LDS port work during MFMA clusters. Same-phase consumption,
//     per-phase reads (8,4,8,4), single vmcnt(6) per K-tile at ph3.
// ---------------------------------------------------------------------------

#define M_DIM 4096
#define N_DIM 4096
#define K_DIM 4096

typedef __attribute__((ext_vector_type(8))) short bf16x8;   // 8 bf16 = 4 VGPRs
typedef __attribute__((ext_vector_type(4))) float f32x4;    // MFMA C/D

__device__ __forceinline__ unsigned short f32_to_bf16_rne(float f) {
    unsigned u = __float_as_uint(f);
    u += 0x7fffu + ((u >> 16) & 1u);   // round-to-nearest-even
    return (unsigned short)(u >> 16);
}

__device__ __forceinline__ void load_lds16(const void* g, void* l) {
    // async global->LDS, 16 B per lane; LDS dest = wave-uniform base + lane*16
    __builtin_amdgcn_global_load_lds(
        (const __attribute__((address_space(1))) unsigned int*)g,
        (__attribute__((address_space(3))) unsigned int*)l, 16, 0, 0);
}

// ---- fused prologue: blocks [0,16384) dequant W, [16384,32768) convert x ---
__global__ __launch_bounds__(256) void prologue_kernel(
        const int* __restrict__ codes, const float* __restrict__ scales,
        unsigned short* __restrict__ W,
        const float* __restrict__ x, unsigned short* __restrict__ xb) {
    const int bid = blockIdx.x;
    if (bid < 16384) {
        const int tid = bid * 256 + threadIdx.x;      // one thread per int4
        const float s = scales[tid >> 3];             // 8 threads share a scale
        const int4 c  = ((const int4*)codes)[tid];
        union { unsigned short u[4]; uint2 v; } p;
        p.u[0] = f32_to_bf16_rne(s * (float)(c.x - 128));
        p.u[1] = f32_to_bf16_rne(s * (float)(c.y - 128));
        p.u[2] = f32_to_bf16_rne(s * (float)(c.z - 128));
        p.u[3] = f32_to_bf16_rne(s * (float)(c.w - 128));
        ((uint2*)W)[tid] = p.v;
    } else {
        const int tid = (bid - 16384) * 256 + threadIdx.x;  // one per float4
        const float4 f = ((const float4*)x)[tid];
        union { unsigned short u[4]; uint2 v; } p;
        p.u[0] = f32_to_bf16_rne(f.x); p.u[1] = f32_to_bf16_rne(f.y);
        p.u[2] = f32_to_bf16_rne(f.z); p.u[3] = f32_to_bf16_rne(f.w);
        ((uint2*)xb)[tid] = p.v;
    }
}

// ---- sync primitives: NO memory clobbers, NO sched_barriers ---------------
#define BAR()   __builtin_amdgcn_s_barrier()
#define LGKM0() asm volatile("s_waitcnt lgkmcnt(0)")
#define VMC(N)  asm volatile("s_waitcnt vmcnt(" #N ")")

// ---- 8-phase 256x256 bf16 GEMM, both operands K-major ----------------------
// LDS: per operand 2 dbuf x 2 khalf regions of [256 rows][32 k] bf16 (16 KB).
// Swizzle: chunk' = chunk ^ ((row>>1)&3); staging pre-swizzles the GLOBAL
//   source k-offset (LDS dest linear); ds_read applies the same XOR ->
//   conflict-free (R4/R7: SQ_LDS_BANK_CONFLICT = 0).
// Phase p: {ds_read own frags | stage 1 half} BAR lgkm0 setprio MFMA setprio
//   BAR. Reads (8,4,8,4): ph0 aX=A(mh0,kh0)+b0r=B(kh0); ph1 aY=A(mh1,kh0)
//   (b0r reused); ph2 aX=A(mh0,kh1)+b1r=B(kh1); ph3 aY=A(mh1,kh1).
// Staging (liveness-verified R5-R7): ph0 Akh1(T+1)->OBUF; ph1 Bkh0(T+2)->BUF
//   (dead since ph0); ph2 Akh0(T+2) (dead since ph1); ph3 Bkh1(T+2) (dead
//   since ph2). vmcnt ledger: carry into T = 6 (three halves of T+1); +8
//   during T; VMC(6)@ph3 completes exactly T+1's four halves, T+2's three
//   stay in flight. Tail: VMC(0)@tile62; tile 63 stages nothing.
__global__ __launch_bounds__(512, 2) void gemm_8phase(
        const unsigned short* __restrict__ A,   // [M,K] bf16 (x)
        const unsigned short* __restrict__ B,   // [N,K] bf16 (W)
        float* __restrict__ C) {                // [M,N] fp32
    __shared__ unsigned short sA[2][2][256 * 32];   // 64 KB
    __shared__ unsigned short sB[2][2][256 * 32];   // 64 KB

    const int tid  = threadIdx.x;
    const int wave = tid >> 6;
    const int lane = tid & 63;

    // XCD rectangle swizzle: xcd = bid%8 owns an 8(m) x 4(n) tile rectangle.
    const int bid  = blockIdx.x;
    const int xcd  = bid & 7;
    const int slot = bid >> 3;                        // 0..31
    const int m0 = ((xcd >> 2) * 8 + (slot >> 2)) * 256;
    const int n0 = ((xcd & 3) * 4 + (slot & 3)) * 256;

    // staging: wave w covers region rows [w*32, w*32+32), 2 calls of 16 rows.
    const int srow   = lane >> 2;
    const int schunk = (lane & 3) ^ ((lane >> 3) & 3);   // pre-swizzled source
    const unsigned short* Ag = A + (size_t)(m0 + wave * 32 + srow) * K_DIM + schunk * 8;
    const unsigned short* Bg = B + (size_t)(n0 + wave * 32 + srow) * K_DIM + schunk * 8;
    const int ldsW = wave * 1024;                        // element offset, call 0

    // fragments: wave (wm,wn) owns C rows [wm*128,+128) x cols [wn*64,+64)
    const int frow = lane & 15;
    const int quad = lane >> 4;
    const int wm = wave >> 2;
    const int wn = wave & 3;
    const int cswz = (quad ^ ((frow >> 1) & 3)) * 8;     // swizzled k-chunk
    const int aOff = (wm * 128 + frow) * 32 + cswz;
    const int bOff = (wn * 64 + frow) * 32 + cswz;

    f32x4 acc[8][4] = {};
    bf16x8 aX[4], aY[4], b0r[4], b1r[4];

#define STG_A(BUF, KH, KT) do { \
        const unsigned short* s_ = Ag + (size_t)(KT) * 64 + (KH) * 32; \
        load_lds16(s_,                       &sA[BUF][KH][ldsW]); \
        load_lds16(s_ + (size_t)16 * K_DIM,  &sA[BUF][KH][ldsW + 512]); \
    } while (0)
#define STG_B(BUF, KH, KT) do { \
        const unsigned short* s_ = Bg + (size_t)(KT) * 64 + (KH) * 32; \
        load_lds16(s_,                       &sB[BUF][KH][ldsW]); \
        load_lds16(s_ + (size_t)16 * K_DIM,  &sB[BUF][KH][ldsW + 512]); \
    } while (0)
#define RD_A4(DST, BUF, KH, MH) do { _Pragma("unroll") \
        for (int i_ = 0; i_ < 4; ++i_) \
            DST[i_] = *(const bf16x8*)&sA[BUF][KH][aOff + ((MH) * 4 + i_) * 512]; \
    } while (0)
#define RD_B4(DST, BUF, KH) do { _Pragma("unroll") \
        for (int i_ = 0; i_ < 4; ++i_) \
            DST[i_] = *(const bf16x8*)&sB[BUF][KH][bOff + i_ * 512]; \
    } while (0)
#define MM16(AR, BR, MH) do { _Pragma("unroll") \
        for (int i_ = 0; i_ < 4; ++i_) { _Pragma("unroll") \
            for (int n_ = 0; n_ < 4; ++n_) \
                acc[(MH) * 4 + i_][n_] = __builtin_amdgcn_mfma_f32_16x16x32_bf16( \
                    AR[i_], BR[n_], acc[(MH) * 4 + i_][n_], 0, 0, 0); \
        } } while (0)

#define KTILE(BUF, OBUF, T, I0, I1, I2, I3, VMF) do { \
        /* ph0: A(mh0,kh0)+B(kh0) -> MFMA mh0 */ \
        RD_A4(aX, BUF, 0, 0); RD_B4(b0r, BUF, 0); \
        if (I0) { STG_A(OBUF, 1, (T) + 1); } \
        BAR(); LGKM0(); \
        __builtin_amdgcn_s_setprio(1); MM16(aX, b0r, 0); __builtin_amdgcn_s_setprio(0); \
        BAR(); \
        /* ph1: A(mh1,kh0) -> MFMA mh1 (b0r reused) */ \
        RD_A4(aY, BUF, 0, 1); \
        if (I1) { STG_B(BUF, 0, (T) + 2); } \
        BAR(); LGKM0(); \
        __builtin_amdgcn_s_setprio(1); MM16(aY, b0r, 1); __builtin_amdgcn_s_setprio(0); \
        BAR(); \
        /* ph2: A(mh0,kh1)+B(kh1) -> MFMA mh0 */ \
        RD_A4(aX, BUF, 1, 0); RD_B4(b1r, BUF, 1); \
        if (I2) { STG_A(BUF, 0, (T) + 2); } \
        BAR(); LGKM0(); \
        __builtin_amdgcn_s_setprio(1); MM16(aX, b1r, 0); __builtin_amdgcn_s_setprio(0); \
        BAR(); \
        /* ph3: A(mh1,kh1) -> MFMA mh1 (b1r reused) */ \
        RD_A4(aY, BUF, 1, 1); \
        if (I3) { STG_B(BUF, 1, (T) + 2); } \
        BAR(); LGKM0(); \
        __builtin_amdgcn_s_setprio(1); MM16(aY, b1r, 1); __builtin_amdgcn_s_setprio(0); \
        VMF; BAR(); \
    } while (0)

    // pipeline prologue: tile 0 all 4 halves + tile 1's {Bkh0,Akh0,Bkh1}
    // (14 loads); vmcnt(6) -> tile 0 resident, 3 halves in flight.
    STG_A(0, 0, 0); STG_B(0, 0, 0); STG_A(0, 1, 0); STG_B(0, 1, 0);
    STG_B(1, 0, 1); STG_A(1, 0, 1); STG_B(1, 1, 1);
    VMC(6); BAR();

#pragma unroll 1
    for (int t2 = 0; t2 < 31; ++t2) {               // tiles 0..61
        const int t = t2 * 2;
        KTILE(0, 1, t,     1, 1, 1, 1, VMC(6));
        KTILE(1, 0, t + 1, 1, 1, 1, 1, VMC(6));
    }
    KTILE(0, 1, 62, 1, 0, 0, 0, VMC(0));            // last issue: Akh1(63)
    KTILE(1, 0, 63, 0, 0, 0, 0, (void)0);

    // epilogue: C/D layout col = lane&15, row = quad*4 + r  [m89/m91]
    const size_t crow0 = (size_t)(m0 + wm * 128 + quad * 4);
    const int    ccol  = n0 + wn * 64 + frow;
#pragma unroll
    for (int mt = 0; mt < 8; ++mt)
#pragma unroll
        for (int nt = 0; nt < 4; ++nt)
#pragma unroll
            for (int r = 0; r < 4; ++r)
                C[(crow0 + mt * 16 + r) * N_DIM + ccol + nt * 16] = acc[mt][nt][r];

#undef STG_A
#undef STG_B
#undef RD_A4
#undef RD_B4
#undef MM16
#undef KTILE
}

extern "C" void kernel_launch(void* const* d_in, const int* in_sizes, int n_in,
                              void* d_out, int out_size, void* d_ws, size_t ws_size,
                              hipStream_t stream) {
    const float* x      = (const float*)d_in[0];   // 2*2048*4096 fp32
    const float* scales = (const float*)d_in[1];   // 4096*128 fp32
    const int*   codes  = (const int*)d_in[2];     // 4096*128*32 int32
    float* y = (float*)d_out;                      // 4096*4096 fp32

    unsigned short* Wb = (unsigned short*)d_ws;                       // 32 MB
    unsigned short* xb = (unsigned short*)((char*)d_ws + (size_t)N_DIM * K_DIM * 2); // 32 MB

    prologue_kernel<<<32768, 256, 0, stream>>>(codes, scales, Wb, x, xb);

    gemm_8phase<<<256, 512, 0, stream>>>(xb, Wb, y);
}

// Round 8
// 283.540 us; speedup vs baseline: 1.0154x; 1.0154x over previous
//
#include <hip/hip_runtime.h>
#include <stdint.h>

// ---------------------------------------------------------------------------
// LazyGGUFLinear: y = x @ dequant(scales, codes)^T   (M=N=K=4096)
// R10: R7's verified addressing (passed, 138.6us) with ONLY the phase
//      skeleton changed: reads -> MFMA -> waits, all waits AFTER the MFMA
//      cluster, ONE barrier per phase. Mechanism: port services the phase's
//      12/4 ds_reads WHILE the matrix pipe runs the MFMA cluster; the
//      end-of-phase LGKM0 pays only max(0, port - mfma) and doubles as the
//      WAR drain for the single barrier. vmcnt: VMC(8) every phase
//      (queue-traced); tail 62=(8,6,4,2), 63=(0,-,-,-). R9's 32x32 +
//      lane-carrying LDS pointer abandoned (correctness failure; two
//      unverified variables at once).
// ---------------------------------------------------------------------------

#define M_DIM 4096
#define N_DIM 4096
#define K_DIM 4096

typedef __attribute__((ext_vector_type(8))) short bf16x8;   // 8 bf16 = 4 VGPRs
typedef __attribute__((ext_vector_type(4))) float f32x4;    // MFMA C/D

__device__ __forceinline__ unsigned short f32_to_bf16_rne(float f) {
    unsigned u = __float_as_uint(f);
    u += 0x7fffu + ((u >> 16) & 1u);   // round-to-nearest-even
    return (unsigned short)(u >> 16);
}

__device__ __forceinline__ void load_lds16(const void* g, void* l) {
    // async global->LDS, 16 B per lane; LDS dest = wave-uniform base + lane*16
    __builtin_amdgcn_global_load_lds(
        (const __attribute__((address_space(1))) unsigned int*)g,
        (__attribute__((address_space(3))) unsigned int*)l, 16, 0, 0);
}

// ---- fused prologue: blocks [0,16384) dequant W, [16384,32768) convert x ---
__global__ __launch_bounds__(256) void prologue_kernel(
        const int* __restrict__ codes, const float* __restrict__ scales,
        unsigned short* __restrict__ W,
        const float* __restrict__ x, unsigned short* __restrict__ xb) {
    const int bid = blockIdx.x;
    if (bid < 16384) {
        const int tid = bid * 256 + threadIdx.x;      // one thread per int4
        const float s = scales[tid >> 3];             // 8 threads share a scale
        const int4 c  = ((const int4*)codes)[tid];
        union { unsigned short u[4]; uint2 v; } p;
        p.u[0] = f32_to_bf16_rne(s * (float)(c.x - 128));
        p.u[1] = f32_to_bf16_rne(s * (float)(c.y - 128));
        p.u[2] = f32_to_bf16_rne(s * (float)(c.z - 128));
        p.u[3] = f32_to_bf16_rne(s * (float)(c.w - 128));
        ((uint2*)W)[tid] = p.v;
    } else {
        const int tid = (bid - 16384) * 256 + threadIdx.x;  // one per float4
        const float4 f = ((const float4*)x)[tid];
        union { unsigned short u[4]; uint2 v; } p;
        p.u[0] = f32_to_bf16_rne(f.x); p.u[1] = f32_to_bf16_rne(f.y);
        p.u[2] = f32_to_bf16_rne(f.z); p.u[3] = f32_to_bf16_rne(f.w);
        ((uint2*)xb)[tid] = p.v;
    }
}

// ---- sync primitives (no memory clobbers anywhere) ------------------------
#define BAR()   __builtin_amdgcn_s_barrier()
#define LGKM0() asm volatile("s_waitcnt lgkmcnt(0)")
#define VMC(N)  asm volatile("s_waitcnt vmcnt(" #N ")")
#define SB0()   __builtin_amdgcn_sched_barrier(0)

// ---- 256x256 bf16 GEMM, K-major operands, read-ahead + waits-after-MFMA ---
// LDS: per operand [2 dbuf][2 khalf][256 rows x 32 k] bf16 (16 KB regions).
// Swizzle: 16B-chunk c' = c ^ ((row>>1)&3); staging pre-swizzles the GLOBAL
//   source k-offset (LDS dest linear, wave-uniform base); ds_read applies the
//   same XOR. Conflict-free (R4-R8: SQ_LDS_BANK_CONFLICT = 0).
// Groups: G0={A(mh0,kh0),B(kh0)} G1={A(mh1,kh0)} G2={A(mh0,kh1),B(kh1)}
//   G3={A(mh1,kh1)}. Phase p: {read G_{p+1}; stage} MFMA G_p; LGKM0; VMC; BAR.
// Stages: ph0 Akh1(T+1)->OBUF[1]; ph1 Bkh0(T+2)->BUF[0]; ph2 Akh0(T+2)->
//   BUF[0]; ph3 Bkh1(T+2)->BUF[1]. (Identical to R7, correctness-proven.)
// WAR (1 barrier/phase): every region's last reads drain at that phase's
//   LGKM0 before its BAR; the region is restaged >=1 barrier later.
// vmcnt queue (2 loads/STG, +2/phase, VMC(8) completes the 2 oldest):
//   item issued at phase P force-completes at P+4, readable P+5; matches
//   every consumer exactly (trace in session notes). Prologue: 14 loads,
//   VMC(6) -> tile 0 resident, 6 in flight.
__global__ __launch_bounds__(512, 2) void gemm_8phase(
        const unsigned short* __restrict__ A,   // [M,K] bf16 (x)
        const unsigned short* __restrict__ B,   // [N,K] bf16 (W)
        float* __restrict__ C) {                // [M,N] fp32
    __shared__ unsigned short sA[2][2][256 * 32];   // 64 KB
    __shared__ unsigned short sB[2][2][256 * 32];   // 64 KB

    const int tid  = threadIdx.x;
    const int wave = tid >> 6;
    const int lane = tid & 63;

    // XCD rectangle swizzle: xcd = bid%8 owns an 8(m) x 4(n) tile rectangle.
    const int bid  = blockIdx.x;
    const int xcd  = bid & 7;
    const int slot = bid >> 3;                        // 0..31
    const int m0 = ((xcd >> 2) * 8 + (slot >> 2)) * 256;
    const int n0 = ((xcd & 3) * 4 + (slot & 3)) * 256;

    // staging: wave w covers region rows [w*32, w*32+32), 2 calls of 16 rows.
    const int srow   = lane >> 2;
    const int schunk = (lane & 3) ^ ((lane >> 3) & 3);   // pre-swizzled source
    const unsigned short* Ag = A + (size_t)(m0 + wave * 32 + srow) * K_DIM + schunk * 8;
    const unsigned short* Bg = B + (size_t)(n0 + wave * 32 + srow) * K_DIM + schunk * 8;
    const int ldsW = wave * 1024;                        // wave-uniform base

    // fragments: wave (wm,wn) owns C rows [wm*128,+128) x cols [wn*64,+64)
    const int frow = lane & 15;
    const int quad = lane >> 4;
    const int wm = wave >> 2;
    const int wn = wave & 3;
    const int cswz = (quad ^ ((frow >> 1) & 3)) * 8;     // swizzled k-chunk
    const int aOff = (wm * 128 + frow) * 32 + cswz;
    const int bOff = (wn * 64 + frow) * 32 + cswz;

    f32x4 acc[8][4] = {};
    bf16x8 aX[4], aY[4], b0r[4], b1r[4];

#define STG_A(BUF, KH, KT) do { \
        const unsigned short* s_ = Ag + (size_t)(KT) * 64 + (KH) * 32; \
        load_lds16(s_,                       &sA[BUF][KH][ldsW]); \
        load_lds16(s_ + (size_t)16 * K_DIM,  &sA[BUF][KH][ldsW + 512]); \
    } while (0)
#define STG_B(BUF, KH, KT) do { \
        const unsigned short* s_ = Bg + (size_t)(KT) * 64 + (KH) * 32; \
        load_lds16(s_,                       &sB[BUF][KH][ldsW]); \
        load_lds16(s_ + (size_t)16 * K_DIM,  &sB[BUF][KH][ldsW + 512]); \
    } while (0)
#define RD_A4(DST, BUF, KH, MH) do { _Pragma("unroll") \
        for (int i_ = 0; i_ < 4; ++i_) \
            DST[i_] = *(const bf16x8*)&sA[BUF][KH][aOff + ((MH) * 4 + i_) * 512]; \
    } while (0)
#define RD_B4(DST, BUF, KH) do { _Pragma("unroll") \
        for (int i_ = 0; i_ < 4; ++i_) \
            DST[i_] = *(const bf16x8*)&sB[BUF][KH][bOff + i_ * 512]; \
    } while (0)
#define MM16(AR, BR, MH) do { _Pragma("unroll") \
        for (int i_ = 0; i_ < 4; ++i_) { _Pragma("unroll") \
            for (int n_ = 0; n_ < 4; ++n_) \
                acc[(MH) * 4 + i_][n_] = __builtin_amdgcn_mfma_f32_16x16x32_bf16( \
                    AR[i_], BR[n_], acc[(MH) * 4 + i_], 0, 0, 0); \
        } } while (0)

// NOTE: MM16 acc operand must be the element, fix in expansion below.
#undef MM16
#define MM16(AR, BR, MH) do { _Pragma("unroll") \
        for (int i_ = 0; i_ < 4; ++i_) { _Pragma("unroll") \
            for (int n_ = 0; n_ < 4; ++n_) \
                acc[(MH) * 4 + i_][n_] = __builtin_amdgcn_mfma_f32_16x16x32_bf16( \
                    AR[i_], BR[n_], acc[(MH) * 4 + i_][n_], 0, 0, 0); \
        } } while (0)

// Phase skeleton: {RD G_{p+1}; STG} SB0 {setprio MFMA G_p setprio} SB0
//   LGKM0 [VMC] BAR SB0.
#define KTILE(BUF, OBUF, T, I0, I1, I2, I3, V0, V1, V2, V3, R3) do { \
        /* ph0: rd G1 | MFMA G0 (aX,b0r -> mh0) */ \
        RD_A4(aY, BUF, 0, 1); \
        if (I0) { STG_A(OBUF, 1, (T) + 1); } \
        SB0(); \
        __builtin_amdgcn_s_setprio(1); MM16(aX, b0r, 0); __builtin_amdgcn_s_setprio(0); \
        SB0(); LGKM0(); V0; BAR(); SB0(); \
        /* ph1: rd G2 | MFMA G1 (aY,b0r -> mh1) */ \
        RD_A4(aX, BUF, 1, 0); RD_B4(b1r, BUF, 1); \
        if (I1) { STG_B(BUF, 0, (T) + 2); } \
        SB0(); \
        __builtin_amdgcn_s_setprio(1); MM16(aY, b0r, 1); __builtin_amdgcn_s_setprio(0); \
        SB0(); LGKM0(); V1; BAR(); SB0(); \
        /* ph2: rd G3 | MFMA G2 (aX,b1r -> mh0) */ \
        RD_A4(aY, BUF, 1, 1); \
        if (I2) { STG_A(BUF, 0, (T) + 2); } \
        SB0(); \
        __builtin_amdgcn_s_setprio(1); MM16(aX, b1r, 0); __builtin_amdgcn_s_setprio(0); \
        SB0(); LGKM0(); V2; BAR(); SB0(); \
        /* ph3: rd G0'(T+1) | MFMA G3 (aY,b1r -> mh1) */ \
        if (R3) { RD_A4(aX, OBUF, 0, 0); RD_B4(b0r, OBUF, 0); } \
        if (I3) { STG_B(BUF, 1, (T) + 2); } \
        SB0(); \
        __builtin_amdgcn_s_setprio(1); MM16(aY, b1r, 1); __builtin_amdgcn_s_setprio(0); \
        SB0(); LGKM0(); V3; BAR(); SB0(); \
    } while (0)

    // pipeline prologue: tile 0 all 4 halves + tile 1's {Bkh0,Akh0,Bkh1}
    // (14 loads); VMC(6) -> tile 0 resident, 3 halves (6 loads) in flight.
    STG_A(0, 0, 0); STG_B(0, 0, 0); STG_A(0, 1, 0); STG_B(0, 1, 0);
    STG_B(1, 0, 1); STG_A(1, 0, 1); STG_B(1, 1, 1);
    VMC(6); BAR(); SB0();
    // initial register stage: G0 of tile 0
    RD_A4(aX, 0, 0, 0); RD_B4(b0r, 0, 0);

#pragma unroll 1
    for (int t2 = 0; t2 < 31; ++t2) {               // tiles 0..61
        const int t = t2 * 2;
        KTILE(0, 1, t,     1, 1, 1, 1, VMC(8), VMC(8), VMC(8), VMC(8), 1);
        KTILE(1, 0, t + 1, 1, 1, 1, 1, VMC(8), VMC(8), VMC(8), VMC(8), 1);
    }
    KTILE(0, 1, 62, 1, 0, 0, 0, VMC(8), VMC(6), VMC(4), VMC(2), 1);
    KTILE(1, 0, 63, 0, 0, 0, 0, VMC(0), (void)0, (void)0, (void)0, 0);

    // epilogue: C/D layout col = lane&15, row = quad*4 + r  [m89/m91]
    const size_t crow0 = (size_t)(m0 + wm * 128 + quad * 4);
    const int    ccol  = n0 + wn * 64 + frow;
#pragma unroll
    for (int mt = 0; mt < 8; ++mt)
#pragma unroll
        for (int nt = 0; nt < 4; ++nt)
#pragma unroll
            for (int r = 0; r < 4; ++r)
                C[(crow0 + mt * 16 + r) * N_DIM + ccol + nt * 16] = acc[mt][nt][r];

#undef STG_A
#undef STG_B
#undef RD_A4
#undef RD_B4
#undef MM16
#undef KTILE
}

extern "C" void kernel_launch(void* const* d_in, const int* in_sizes, int n_in,
                              void* d_out, int out_size, void* d_ws, size_t ws_size,
                              hipStream_t stream) {
    const float* x      = (const float*)d_in[0];   // 2*2048*4096 fp32
    const float* scales = (const float*)d_in[1];   // 4096*128 fp32
    const int*   codes  = (const int*)d_in[2];     // 4096*128*32 int32
    float* y = (float*)d_out;                      // 4096*4096 fp32

    unsigned short* Wb = (unsigned short*)d_ws;                       // 32 MB
    unsigned short* xb = (unsigned short*)((char*)d_ws + (size_t)N_DIM * K_DIM * 2); // 32 MB

    prologue_kernel<<<32768, 256, 0, stream>>>(codes, scales, Wb, x, xb);

    gemm_8phase<<<256, 512, 0, stream>>>(xb, Wb, y);
}